// Round 7
// baseline (268.557 us; speedup 1.0000x reference)
//
#include <hip/hip_runtime.h>

// LinearGaussianTree, MI355X. 8192 rows; per row a 4095-node binary tree:
// s_i = w_i * s_parent + (1-w_i)*SCALE*noise_i. Outputs fp32 flat:
// samples (8192x4095), ms (8192x4094), scales (8192x4094), reverse level
// order; root = samples col 4094. Column identity: parent = (c>>1)+2048
// (valid for EVERY non-root column c in 0..4093).
//
// r7: stream-purity decomposition.
//  K1 lgt_samp: r5's tree kernel writing ONLY samples (1R+1W, copy-like mix).
//  K2 lgt_msc:  uniform elementwise pass: ms[c] = w[c]*samples[(c>>1)+2048],
//               scales[c] = sc[c]. Reads just-written samples (L3-warm),
//               writes 2 streams with regular f4 stores, no sync.

constexpr int   kRows  = 8192;
constexpr float kScale = 0.1f;

typedef float f4_ __attribute__((ext_vector_type(4)));
typedef float f2_ __attribute__((ext_vector_type(2)));
typedef f4_ f4u __attribute__((aligned(4)));   // 16B vector, 4B-aligned ok
typedef f2_ f2u __attribute__((aligned(4)));

// Column-ordered (w, sc) table. Zero-init BSS; rewritten every launch.
__device__ __align__(16) float2 g_tab[4096];

__global__ __launch_bounds__(256) void lgt_precompute(
    const float* __restrict__ weights)
{
    int t = blockIdx.x * 256 + threadIdx.x;      // tree index 0..4093
    if (t < 4094) {
        int d = 31 - __clz(t + 2);               // level of node t
        int c = t + 4098 - 3 * (1 << d);         // output column
        float w = 1.0f / (1.0f + __expf(-weights[t]));
        g_tab[c] = make_float2(w, (1.0f - w) * kScale);
    }
}

// Barrier that does NOT drain vmcnt (LDS visibility only).
__device__ __forceinline__ void lgkm_barrier() {
    __builtin_amdgcn_sched_barrier(0);
    asm volatile("s_waitcnt lgkmcnt(0)" ::: "memory");
    __builtin_amdgcn_s_barrier();
    __builtin_amdgcn_sched_barrier(0);
}

// ---- K1: tree build, samples only ----
__global__ __launch_bounds__(256) void lgt_samp(
    const float* __restrict__ noise_root,
    const float* __restrict__ noise_rest,
    float* __restrict__ samples)
{
    __shared__ float sL[256];                    // cols 3840..4095 (root @254)

    const int row = blockIdx.x;
    const int tid = threadIdx.x;
    const float* __restrict__ nr = noise_rest + (size_t)row * 4094;
    float* __restrict__ sr = samples + (size_t)row * 4095;

    // prefetch all of this row's noise (one latency for everything)
    const float nzs = nr[tid];                   // levels 1..7
    const float n8  = nr[254 + tid];
    const f2_  n9   = *(const f2_*)(nr + 510 + 2 * tid);
    const f2_  nA0  = *(const f2_*)(nr + 1022 + 4 * tid);
    const f2_  nA1  = *(const f2_*)(nr + 1022 + 4 * tid + 2);
    f2_ nL[4];
    #pragma unroll
    for (int k = 0; k < 4; ++k)
        nL[k] = *(const f2_*)(nr + 2046 + 8 * tid + 2 * k);
    const float rootv = noise_root[row];         // IN_SCALE == 1.0

    if (tid == 0) { sL[254] = rootv; sr[4094] = rootv; }
    lgkm_barrier();

    // phase A: levels 1..7 in LDS
    #pragma unroll
    for (int d = 1; d <= 7; ++d) {
        const int off     = (1 << d) - 2;
        const int n       = 1 << d;
        const int colbase = 4096 - (n << 1);
        if (tid >= off && tid < off + n) {
            const int c = colbase + (tid - off);
            const float2 t2 = g_tab[c];
            const float  p  = sL[(c >> 1) - 1792];
            const float  v  = fmaf(t2.y, nzs, t2.x * p);
            sL[c - 3840] = v;
            sr[c] = v;
        }
        lgkm_barrier();
    }

    // phase B: per-thread subtree (levels 8..11), barrier-free
    const float a7 = sL[tid >> 1];

    const float2 t8 = g_tab[3584 + tid];
    const float  v8 = fmaf(t8.y, n8, t8.x * a7);
    sr[3584 + tid] = v8;

    const f4_ t9 = *(const f4_*)(&g_tab[3072 + 2 * tid]);
    const float v90 = fmaf(t9.y, n9.x, t9.x * v8);
    const float v91 = fmaf(t9.w, n9.y, t9.z * v8);
    {
        f2_ sv; sv.x = v90; sv.y = v91;
        *(f2u*)(sr + 3072 + 2 * tid) = sv;
    }

    const f4_ tA = *(const f4_*)(&g_tab[2048 + 4 * tid]);
    const f4_ tB = *(const f4_*)(&g_tab[2048 + 4 * tid + 2]);
    const float vA0 = fmaf(tA.y, nA0.x, tA.x * v90);
    const float vA1 = fmaf(tA.w, nA0.y, tA.z * v90);
    const float vA2 = fmaf(tB.y, nA1.x, tB.x * v91);
    const float vA3 = fmaf(tB.w, nA1.y, tB.z * v91);
    {
        f4_ sv; sv.x = vA0; sv.y = vA1; sv.z = vA2; sv.w = vA3;
        *(f4u*)(sr + 2048 + 4 * tid) = sv;
    }

    const float pv[4] = { vA0, vA1, vA2, vA3 };
    float sv[8];
    #pragma unroll
    for (int k = 0; k < 4; ++k) {
        const f4_  t = *(const f4_*)(&g_tab[8 * tid + 2 * k]);
        const float p = pv[k];
        sv[2 * k]     = fmaf(t.y, nL[k].x, t.x * p);
        sv[2 * k + 1] = fmaf(t.w, nL[k].y, t.z * p);
    }
    {
        f4_ a, b;
        a.x = sv[0]; a.y = sv[1]; a.z = sv[2]; a.w = sv[3];
        b.x = sv[4]; b.y = sv[5]; b.z = sv[6]; b.w = sv[7];
        *(f4u*)(sr + 8 * tid)     = a;
        *(f4u*)(sr + 8 * tid + 4) = b;
    }
}

// ---- K2: ms + scales, uniform elementwise over all columns ----
__global__ __launch_bounds__(256) void lgt_msc(
    const float* __restrict__ samples,
    float* __restrict__ ms,
    float* __restrict__ scales)
{
    const int row = blockIdx.x;
    const int t   = threadIdx.x;
    const float* __restrict__ sp = samples + (size_t)row * 4095;
    float* __restrict__ mr = ms     + (size_t)row * 4094;
    float* __restrict__ cr = scales + (size_t)row * 4094;

    #pragma unroll
    for (int i = 0; i < 4; ++i) {
        const int c = (t << 4) + (i << 2);       // 16t + 4i
        if (c + 3 < 4094) {
            const f4_ ta = *(const f4_*)(&g_tab[c]);      // w0,sc0,w1,sc1
            const f4_ tb = *(const f4_*)(&g_tab[c + 2]);  // w2,sc2,w3,sc3
            const f2u pp = *(const f2u*)(sp + (c >> 1) + 2048);
            f4_ mv, cv;
            mv.x = ta.x * pp.x; mv.y = ta.z * pp.x;
            mv.z = tb.x * pp.y; mv.w = tb.z * pp.y;
            cv.x = ta.y; cv.y = ta.w; cv.z = tb.y; cv.w = tb.w;
            *(f4u*)(mr + c) = mv;
            *(f4u*)(cr + c) = cv;
        } else {
            #pragma unroll
            for (int e = 0; e < 4; ++e) {
                const int ce = c + e;
                if (ce < 4094) {
                    const float2 tt = g_tab[ce];
                    mr[ce] = tt.x * sp[(ce >> 1) + 2048];
                    cr[ce] = tt.y;
                }
            }
        }
    }
}

extern "C" void kernel_launch(void* const* d_in, const int* in_sizes, int n_in,
                              void* d_out, int out_size, void* d_ws, size_t ws_size,
                              hipStream_t stream)
{
    const float* weights    = (const float*)d_in[0];
    const float* noise_root = (const float*)d_in[1];
    const float* noise_rest = (const float*)d_in[2];

    float* out     = (float*)d_out;
    float* samples = out;
    float* ms      = samples + (size_t)kRows * 4095;
    float* scales  = ms      + (size_t)kRows * 4094;

    lgt_precompute<<<(4094 + 255) / 256, 256, 0, stream>>>(weights);
    lgt_samp<<<kRows, 256, 0, stream>>>(noise_root, noise_rest, samples);
    lgt_msc<<<kRows, 256, 0, stream>>>(samples, ms, scales);
}

// Round 8
// 141.439 us; speedup vs baseline: 1.8987x; 1.8987x over previous
//
#include <hip/hip_runtime.h>

// LinearGaussianTree, MI355X. 8192 rows; per row a 4095-node binary tree:
// s_i = w_i * s_parent + (1-w_i)*SCALE*noise_i. Outputs fp32 flat:
// samples (8192x4095), ms (8192x4094), scales (8192x4094), reverse level
// order; root = samples col 4094. Column identity: parent = (c>>1)+2048.
//
// r8: ZERO-SYNC kernel. No barriers, no LDS, no inter-wave deps.
// Each of the 4 waves in a block redundantly computes levels 1..7 of the
// block's row via __shfl (levels 1..6: node i on lane i; level 7: nodes
// 2l,2l+1 on lane l). Thread t = 64w+l then pulls its level-7 ancestor
// in-wave (j = t>>1 lives on lane 16w+(l>>2), slot (l>>1)&1) and computes
// its private level-8 subtree (15 nodes) exactly as r5. Wave 0 stores the
// top-level outputs (254*3 values); everyone stores their subtree.

constexpr int   kRows  = 8192;
constexpr float kScale = 0.1f;

typedef float f4_ __attribute__((ext_vector_type(4)));
typedef float f2_ __attribute__((ext_vector_type(2)));
typedef f4_ f4u __attribute__((aligned(4)));   // 16B vector, 4B-aligned ok
typedef f2_ f2u __attribute__((aligned(4)));

// Column-ordered (w, sc) table. Zero-init BSS; rewritten every launch.
__device__ __align__(16) float2 g_tab[4096];

__global__ __launch_bounds__(256) void lgt_precompute(
    const float* __restrict__ weights)
{
    int t = blockIdx.x * 256 + threadIdx.x;      // tree index 0..4093
    if (t < 4094) {
        int d = 31 - __clz(t + 2);               // level of node t
        int c = t + 4098 - 3 * (1 << d);         // output column
        float w = 1.0f / (1.0f + __expf(-weights[t]));
        g_tab[c] = make_float2(w, (1.0f - w) * kScale);
    }
}

__global__ __launch_bounds__(256) void lgt_main(
    const float* __restrict__ noise_root,
    const float* __restrict__ noise_rest,
    float* __restrict__ samples,
    float* __restrict__ ms,
    float* __restrict__ scales)
{
    const int row  = blockIdx.x;
    const int tid  = threadIdx.x;
    const int lane = tid & 63;
    const int wv   = tid >> 6;

    const float* __restrict__ nr = noise_rest + (size_t)row * 4094;
    float* __restrict__ sr = samples + (size_t)row * 4095;
    float* __restrict__ mr = ms      + (size_t)row * 4094;
    float* __restrict__ cr = scales  + (size_t)row * 4094;

    // ---- subtree noise prefetch (one latency, overlaps top compute) ----
    const float n8  = nr[254 + tid];
    const f2_  n9   = *(const f2_*)(nr + 510 + 2 * tid);
    const f2_  nA0  = *(const f2_*)(nr + 1022 + 4 * tid);
    const f2_  nA1  = *(const f2_*)(nr + 1022 + 4 * tid + 2);
    f2_ nL[4];
    #pragma unroll
    for (int k = 0; k < 4; ++k)
        nL[k] = *(const f2_*)(nr + 2046 + 8 * tid + 2 * k);

    const float rootv = noise_root[row];         // IN_SCALE == 1.0
    if (tid == 0) sr[4094] = rootv;

    // ---- top: levels 1..6 via shfl (every wave, redundant) ----
    float v = rootv;
    #pragma unroll
    for (int d = 1; d <= 6; ++d) {
        const int off     = (1 << d) - 2;
        const int n       = 1 << d;
        const int colbase = 4096 - (n << 1);
        const int i       = lane & (n - 1);      // node-local (aliased dup)
        const float p  = (d == 1) ? rootv : __shfl(v, lane >> 1);
        const float2 t2 = g_tab[colbase + i];
        const float  nz = nr[off + i];
        const float  m  = t2.x * p;
        v = fmaf(t2.y, nz, m);
        if (wv == 0 && lane < n) {
            const int c = colbase + lane;
            sr[c] = v; mr[c] = m; cr[c] = t2.y;
        }
    }

    // ---- level 7: nodes 2l, 2l+1 (cols 3840+2l), parent = own v ----
    const f4_ t7 = *(const f4_*)(&g_tab[3840 + 2 * lane]);   // 16B-aligned
    const f2_ n7 = *(const f2_*)(nr + 126 + 2 * lane);
    const float m70 = t7.x * v,  m71 = t7.z * v;
    const float v70 = fmaf(t7.y, n7.x, m70);
    const float v71 = fmaf(t7.w, n7.y, m71);
    if (wv == 0) {
        const int c = 3840 + 2 * lane;
        f2_ sv; sv.x = v70; sv.y = v71;
        f2_ mv; mv.x = m70; mv.y = m71;
        f2_ cv; cv.x = t7.y; cv.y = t7.w;
        *(f2u*)(sr + c) = sv;
        *(f2_*)(mr + c) = mv;        // row*4094 + c even -> 8B-aligned
        *(f2_*)(cr + c) = cv;
    }

    // ---- level-7 ancestor for subtree tid: j = tid>>1 on lane 16wv+(l>>2) --
    const int   src = (wv << 4) + (lane >> 2);
    const float a70 = __shfl(v70, src);
    const float a71 = __shfl(v71, src);
    const float a7  = ((lane >> 1) & 1) ? a71 : a70;

    // ---- phase B: per-thread subtree (levels 8..11), as r5 ----
    const float2 t8 = g_tab[3584 + tid];
    const float  m8 = t8.x * a7;
    const float  v8 = fmaf(t8.y, n8, m8);
    sr[3584 + tid] = v8; mr[3584 + tid] = m8; cr[3584 + tid] = t8.y;

    const f4_ t9 = *(const f4_*)(&g_tab[3072 + 2 * tid]);
    const float m90 = t9.x * v8, m91 = t9.z * v8;
    const float v90 = fmaf(t9.y, n9.x, m90);
    const float v91 = fmaf(t9.w, n9.y, m91);
    {
        f2_ sv; sv.x = v90; sv.y = v91;
        f2_ mv; mv.x = m90; mv.y = m91;
        f2_ cv; cv.x = t9.y; cv.y = t9.w;
        *(f2u*)(sr + 3072 + 2 * tid) = sv;
        *(f2_*)(mr + 3072 + 2 * tid) = mv;
        *(f2_*)(cr + 3072 + 2 * tid) = cv;
    }

    const f4_ tA = *(const f4_*)(&g_tab[2048 + 4 * tid]);
    const f4_ tB = *(const f4_*)(&g_tab[2048 + 4 * tid + 2]);
    const float mA0 = tA.x * v90, mA1 = tA.z * v90;
    const float mA2 = tB.x * v91, mA3 = tB.z * v91;
    const float vA0 = fmaf(tA.y, nA0.x, mA0);
    const float vA1 = fmaf(tA.w, nA0.y, mA1);
    const float vA2 = fmaf(tB.y, nA1.x, mA2);
    const float vA3 = fmaf(tB.w, nA1.y, mA3);
    {
        f4_ sv; sv.x = vA0; sv.y = vA1; sv.z = vA2; sv.w = vA3;
        f4_ mv; mv.x = mA0; mv.y = mA1; mv.z = mA2; mv.w = mA3;
        f4_ cv; cv.x = tA.y; cv.y = tA.w; cv.z = tB.y; cv.w = tB.w;
        *(f4u*)(sr + 2048 + 4 * tid) = sv;
        *(f4u*)(mr + 2048 + 4 * tid) = mv;
        *(f4u*)(cr + 2048 + 4 * tid) = cv;
    }

    const float pv[4] = { vA0, vA1, vA2, vA3 };
    float sv[8], mv[8], cv[8];
    #pragma unroll
    for (int k = 0; k < 4; ++k) {
        const f4_  t = *(const f4_*)(&g_tab[8 * tid + 2 * k]);
        const float p = pv[k];
        const float m0 = t.x * p, m1 = t.z * p;
        sv[2 * k]     = fmaf(t.y, nL[k].x, m0);
        sv[2 * k + 1] = fmaf(t.w, nL[k].y, m1);
        mv[2 * k] = m0; mv[2 * k + 1] = m1;
        cv[2 * k] = t.y; cv[2 * k + 1] = t.w;
    }
    {
        f4_ a, b;
        a.x = sv[0]; a.y = sv[1]; a.z = sv[2]; a.w = sv[3];
        b.x = sv[4]; b.y = sv[5]; b.z = sv[6]; b.w = sv[7];
        *(f4u*)(sr + 8 * tid)     = a;
        *(f4u*)(sr + 8 * tid + 4) = b;
        a.x = mv[0]; a.y = mv[1]; a.z = mv[2]; a.w = mv[3];
        b.x = mv[4]; b.y = mv[5]; b.z = mv[6]; b.w = mv[7];
        *(f4u*)(mr + 8 * tid)     = a;
        *(f4u*)(mr + 8 * tid + 4) = b;
        a.x = cv[0]; a.y = cv[1]; a.z = cv[2]; a.w = cv[3];
        b.x = cv[4]; b.y = cv[5]; b.z = cv[6]; b.w = cv[7];
        *(f4u*)(cr + 8 * tid)     = a;
        *(f4u*)(cr + 8 * tid + 4) = b;
    }
}

extern "C" void kernel_launch(void* const* d_in, const int* in_sizes, int n_in,
                              void* d_out, int out_size, void* d_ws, size_t ws_size,
                              hipStream_t stream)
{
    const float* weights    = (const float*)d_in[0];
    const float* noise_root = (const float*)d_in[1];
    const float* noise_rest = (const float*)d_in[2];

    float* out     = (float*)d_out;
    float* samples = out;
    float* ms      = samples + (size_t)kRows * 4095;
    float* scales  = ms      + (size_t)kRows * 4094;

    lgt_precompute<<<(4094 + 255) / 256, 256, 0, stream>>>(weights);
    lgt_main<<<kRows, 256, 0, stream>>>(noise_root, noise_rest,
                                        samples, ms, scales);
}

// Round 9
// 139.207 us; speedup vs baseline: 1.9292x; 1.0160x over previous
//
#include <hip/hip_runtime.h>

// LinearGaussianTree, MI355X. 8192 rows; per row a 4095-node binary tree:
// s_i = w_i * s_parent + (1-w_i)*SCALE*noise_i. Outputs fp32 flat:
// samples (8192x4095), ms (8192x4094), scales (8192x4094), reverse level
// order; root = samples col 4094. Column identity: parent = (c>>1)+2048.
//
// r9: stream-purity decomposition with CORRECT wave-contiguous layouts.
//  K1 lgt_samp:   tree -> samples only (noise-R + samples-W, copy-like).
//  K2 lgt_ms:     ms[c] = w[c] * samples[(c>>1)+2048] (L3-warm R + 1 W).
//  K3 lgt_scales: scales[c] = sc[c] (pure broadcast fill, 1 W).
// K2/K3 chunking: c = 1024k + 4t -> every store instruction is 64 lanes x
// 16B contiguous (full-line), unlike r7's broken per-thread-contiguous map.

constexpr int   kRows  = 8192;
constexpr float kScale = 0.1f;

typedef float f4_ __attribute__((ext_vector_type(4)));
typedef float f2_ __attribute__((ext_vector_type(2)));
typedef f4_ f4u __attribute__((aligned(4)));   // 16B vector, 4B-aligned ok
typedef f2_ f2u __attribute__((aligned(4)));

// Column-ordered (w, sc) table. Zero-init BSS; rewritten every launch.
__device__ __align__(16) float2 g_tab[4096];

__global__ __launch_bounds__(256) void lgt_precompute(
    const float* __restrict__ weights)
{
    int t = blockIdx.x * 256 + threadIdx.x;      // tree index 0..4093
    if (t < 4094) {
        int d = 31 - __clz(t + 2);               // level of node t
        int c = t + 4098 - 3 * (1 << d);         // output column
        float w = 1.0f / (1.0f + __expf(-weights[t]));
        g_tab[c] = make_float2(w, (1.0f - w) * kScale);
    }
}

// Barrier that does NOT drain vmcnt (LDS visibility only).
__device__ __forceinline__ void lgkm_barrier() {
    __builtin_amdgcn_sched_barrier(0);
    asm volatile("s_waitcnt lgkmcnt(0)" ::: "memory");
    __builtin_amdgcn_s_barrier();
    __builtin_amdgcn_sched_barrier(0);
}

// ---- K1: tree build, samples only (r7-proven) ----
__global__ __launch_bounds__(256) void lgt_samp(
    const float* __restrict__ noise_root,
    const float* __restrict__ noise_rest,
    float* __restrict__ samples)
{
    __shared__ float sL[256];                    // cols 3840..4095 (root @254)

    const int row = blockIdx.x;
    const int tid = threadIdx.x;
    const float* __restrict__ nr = noise_rest + (size_t)row * 4094;
    float* __restrict__ sr = samples + (size_t)row * 4095;

    // prefetch all of this row's noise (one latency for everything)
    const float nzs = nr[tid];                   // levels 1..7
    const float n8  = nr[254 + tid];
    const f2_  n9   = *(const f2_*)(nr + 510 + 2 * tid);
    const f2_  nA0  = *(const f2_*)(nr + 1022 + 4 * tid);
    const f2_  nA1  = *(const f2_*)(nr + 1022 + 4 * tid + 2);
    f2_ nL[4];
    #pragma unroll
    for (int k = 0; k < 4; ++k)
        nL[k] = *(const f2_*)(nr + 2046 + 8 * tid + 2 * k);
    const float rootv = noise_root[row];         // IN_SCALE == 1.0

    if (tid == 0) { sL[254] = rootv; sr[4094] = rootv; }
    lgkm_barrier();

    // phase A: levels 1..7 in LDS
    #pragma unroll
    for (int d = 1; d <= 7; ++d) {
        const int off     = (1 << d) - 2;
        const int n       = 1 << d;
        const int colbase = 4096 - (n << 1);
        if (tid >= off && tid < off + n) {
            const int c = colbase + (tid - off);
            const float2 t2 = g_tab[c];
            const float  p  = sL[(c >> 1) - 1792];
            const float  v  = fmaf(t2.y, nzs, t2.x * p);
            sL[c - 3840] = v;
            sr[c] = v;
        }
        lgkm_barrier();
    }

    // phase B: per-thread subtree (levels 8..11), barrier-free
    const float a7 = sL[tid >> 1];

    const float2 t8 = g_tab[3584 + tid];
    const float  v8 = fmaf(t8.y, n8, t8.x * a7);
    sr[3584 + tid] = v8;

    const f4_ t9 = *(const f4_*)(&g_tab[3072 + 2 * tid]);
    const float v90 = fmaf(t9.y, n9.x, t9.x * v8);
    const float v91 = fmaf(t9.w, n9.y, t9.z * v8);
    {
        f2_ sv; sv.x = v90; sv.y = v91;
        *(f2u*)(sr + 3072 + 2 * tid) = sv;
    }

    const f4_ tA = *(const f4_*)(&g_tab[2048 + 4 * tid]);
    const f4_ tB = *(const f4_*)(&g_tab[2048 + 4 * tid + 2]);
    const float vA0 = fmaf(tA.y, nA0.x, tA.x * v90);
    const float vA1 = fmaf(tA.w, nA0.y, tA.z * v90);
    const float vA2 = fmaf(tB.y, nA1.x, tB.x * v91);
    const float vA3 = fmaf(tB.w, nA1.y, tB.z * v91);
    {
        f4_ sv; sv.x = vA0; sv.y = vA1; sv.z = vA2; sv.w = vA3;
        *(f4u*)(sr + 2048 + 4 * tid) = sv;
    }

    const float pv[4] = { vA0, vA1, vA2, vA3 };
    float sv[8];
    #pragma unroll
    for (int k = 0; k < 4; ++k) {
        const f4_  t = *(const f4_*)(&g_tab[8 * tid + 2 * k]);
        const float p = pv[k];
        sv[2 * k]     = fmaf(t.y, nL[k].x, t.x * p);
        sv[2 * k + 1] = fmaf(t.w, nL[k].y, t.z * p);
    }
    {
        f4_ a, b;
        a.x = sv[0]; a.y = sv[1]; a.z = sv[2]; a.w = sv[3];
        b.x = sv[4]; b.y = sv[5]; b.z = sv[6]; b.w = sv[7];
        *(f4u*)(sr + 8 * tid)     = a;
        *(f4u*)(sr + 8 * tid + 4) = b;
    }
}

// ---- K2: ms = w[c] * samples_parent (wave-contiguous chunks) ----
__global__ __launch_bounds__(256) void lgt_ms(
    const float* __restrict__ samples,
    float* __restrict__ ms)
{
    const int row = blockIdx.x;
    const int t   = threadIdx.x;
    const float* __restrict__ sp = samples + (size_t)row * 4095;
    float* __restrict__ mr = ms + (size_t)row * 4094;

    #pragma unroll
    for (int k = 0; k < 4; ++k) {
        const int c = (k << 10) + (t << 2);      // 1024k + 4t: wave-contiguous
        if (c + 3 < 4094) {
            const f4_ ta = *(const f4_*)(&g_tab[c]);      // w0,sc0,w1,sc1
            const f4_ tb = *(const f4_*)(&g_tab[c + 2]);  // w2,sc2,w3,sc3
            const f2u pp = *(const f2u*)(sp + (c >> 1) + 2048);
            f4_ mv;
            mv.x = ta.x * pp.x; mv.y = ta.z * pp.x;
            mv.z = tb.x * pp.y; mv.w = tb.z * pp.y;
            *(f4u*)(mr + c) = mv;
        } else if (c < 4094) {                   // tail: c = 4092 only
            #pragma unroll
            for (int e = 0; e < 4; ++e) {
                const int ce = c + e;
                if (ce < 4094)
                    mr[ce] = g_tab[ce].x * sp[(ce >> 1) + 2048];
            }
        }
    }
}

// ---- K3: scales broadcast fill (wave-contiguous chunks) ----
__global__ __launch_bounds__(256) void lgt_scales(
    float* __restrict__ scales)
{
    const int row = blockIdx.x;
    const int t   = threadIdx.x;
    float* __restrict__ cr = scales + (size_t)row * 4094;

    #pragma unroll
    for (int k = 0; k < 4; ++k) {
        const int c = (k << 10) + (t << 2);
        if (c + 3 < 4094) {
            const f4_ ta = *(const f4_*)(&g_tab[c]);
            const f4_ tb = *(const f4_*)(&g_tab[c + 2]);
            f4_ cv;
            cv.x = ta.y; cv.y = ta.w; cv.z = tb.y; cv.w = tb.w;
            *(f4u*)(cr + c) = cv;
        } else if (c < 4094) {
            #pragma unroll
            for (int e = 0; e < 4; ++e) {
                const int ce = c + e;
                if (ce < 4094) cr[ce] = g_tab[ce].y;
            }
        }
    }
}

extern "C" void kernel_launch(void* const* d_in, const int* in_sizes, int n_in,
                              void* d_out, int out_size, void* d_ws, size_t ws_size,
                              hipStream_t stream)
{
    const float* weights    = (const float*)d_in[0];
    const float* noise_root = (const float*)d_in[1];
    const float* noise_rest = (const float*)d_in[2];

    float* out     = (float*)d_out;
    float* samples = out;
    float* ms      = samples + (size_t)kRows * 4095;
    float* scales  = ms      + (size_t)kRows * 4094;

    lgt_precompute<<<(4094 + 255) / 256, 256, 0, stream>>>(weights);
    lgt_samp<<<kRows, 256, 0, stream>>>(noise_root, noise_rest, samples);
    lgt_ms<<<kRows, 256, 0, stream>>>(samples, ms);
    lgt_scales<<<kRows, 256, 0, stream>>>(scales);
}